// Round 1
// baseline (449.393 us; speedup 1.0000x reference)
//
#include <hip/hip_runtime.h>

// out[n] = image[3*(n/3) + perm[n]], N = 4096*4096*3 floats.
// R5: latency-bound fix. R4 had 3 serialized memory round trips per wave
// (img/perm load -> wait; ds_bpermute -> wait; lane0/63 branch loads -> wait)
// with only one chunk of work per thread. R5:
//  - ITERS=3 chunks per thread, ALL loads issued independently up front
//    (12 loads / 9KB per wave in flight before the single vmcnt wait).
//  - Shuffles + edge branches replaced by two clamped float2 loads per chunk
//    (img[4c-2..4c-1], img[4c+4..4c+5]) - same cache lines, no DS pipe,
//    no exec-mask divergence.
//  - Candidate offset from p = c % 3 (4 == 1 mod 3), incremented per chunk
//    (256 == 1 mod 3): kills the per-element (n/3)*3 magic-division.
//  - Non-temporal stores: out (201MB) is never re-read; keep it out of the
//    256MB L3 so the 402MB of inputs get the capacity.

typedef float f32x2 __attribute__((ext_vector_type(2)));
typedef float f32x4 __attribute__((ext_vector_type(4)));
typedef int   i32x4 __attribute__((ext_vector_type(4)));

#define ITERS 3

__device__ __forceinline__ float sel8(float c0, float c1, float c2, float c3,
                                      float c4, float c5, float c6, float c7,
                                      int idx) {
    // 8-way select, 7 v_cndmask tree (idx in [0,7])
    float s01 = (idx & 1) ? c1 : c0;
    float s23 = (idx & 1) ? c3 : c2;
    float s45 = (idx & 1) ? c5 : c4;
    float s67 = (idx & 1) ? c7 : c6;
    float s03 = (idx & 2) ? s23 : s01;
    float s47 = (idx & 2) ? s67 : s45;
    return (idx & 4) ? s47 : s03;
}

__global__ __launch_bounds__(256) void PerPixelChannelPermutation_kernel(
    const float* __restrict__ img, const i32x4* __restrict__ perm4,
    f32x4* __restrict__ out4, int nchunks, int n_elems) {
    const int tid = threadIdx.x;
    const int c0  = blockIdx.x * (256 * ITERS) + tid;
    if (c0 >= nchunks) return;  // later iters are even larger; all OOB

    const f32x4* img4 = (const f32x4*)img;

    f32x4 v[ITERS];
    f32x2 lo[ITERS];
    f32x2 hi[ITERS];
    i32x4 q[ITERS];

    // Phase 1: issue every load, no consumption -> one vmcnt drain total.
#pragma unroll
    for (int i = 0; i < ITERS; ++i) {
        int c = c0 + i * 256;
        if (c >= nchunks) c = c0;        // tail clamp (re-load chunk c0; store is guarded)
        const int c4 = c * 4;
        v[i] = img4[c];                  // img[4c .. 4c+3], coalesced 16B/lane
        int bl = c4 - 2; if (bl < 0) bl = 0;                       // only chunk 0 (unreachable cands)
        int bh = c4 + 4; if (bh > n_elems - 2) bh = n_elems - 2;   // only last chunk (unreachable)
        lo[i] = *(const f32x2*)(img + bl);   // img[4c-2 .. 4c-1], 8B-aligned
        hi[i] = *(const f32x2*)(img + bh);   // img[4c+4 .. 4c+5], 16B-aligned
        q[i]  = perm4[c];                // perm[4c .. 4c+3], coalesced 16B/lane
    }

    // Phase 2: compute + store. p = (4*c) % 3 = c % 3; stride 256 == 1 mod 3.
    const int p0 = c0 % 3;  // compiler emits one magic-mul sequence
#pragma unroll
    for (int i = 0; i < ITERS; ++i) {
        const int c = c0 + i * 256;
        int p = p0 + i;
        if (p >= 3) p -= 3;  // i <= 2, p0 <= 2 -> one wrap suffices

        // out[4c+k] = img[pixel_base(4c+k) + perm_k]; candidate index
        // idx_k = off_k + perm_k over [lo.x,lo.y,v.x,v.y,v.z,v.w,hi.x,hi.y]
        //   p=0: offs {2,2,2,5}   p=1: {1,1,4,4}   p=2: {0,3,3,3}
        const int off0 = 2 - p;
        const int off3 = 5 - p;
        const int off1 = (p == 0) ? 2 : ((p == 1) ? 1 : 3);
        const int off2 = (p == 0) ? 2 : ((p == 1) ? 4 : 3);

        f32x4 o;
        o.x = sel8(lo[i].x, lo[i].y, v[i].x, v[i].y, v[i].z, v[i].w,
                   hi[i].x, hi[i].y, off0 + q[i].x);
        o.y = sel8(lo[i].x, lo[i].y, v[i].x, v[i].y, v[i].z, v[i].w,
                   hi[i].x, hi[i].y, off1 + q[i].y);
        o.z = sel8(lo[i].x, lo[i].y, v[i].x, v[i].y, v[i].z, v[i].w,
                   hi[i].x, hi[i].y, off2 + q[i].z);
        o.w = sel8(lo[i].x, lo[i].y, v[i].x, v[i].y, v[i].z, v[i].w,
                   hi[i].x, hi[i].y, off3 + q[i].w);

        if (c < nchunks) {
            __builtin_nontemporal_store(o, &out4[c]);  // coalesced, L3-bypass
        }
    }
}

extern "C" void kernel_launch(void* const* d_in, const int* in_sizes, int n_in,
                              void* d_out, int out_size, void* d_ws, size_t ws_size,
                              hipStream_t stream) {
    const float* img   = (const float*)d_in[0];
    const i32x4* perm4 = (const i32x4*)d_in[1];
    f32x4*       out4  = (f32x4*)d_out;

    const int n_elems = in_sizes[0];   // 4096*4096*3 = 50,331,648
    const int nchunks = n_elems / 4;   // one float4 of output per chunk

    const int block = 256;
    const int per_block = block * ITERS;
    const int grid = (nchunks + per_block - 1) / per_block;
    PerPixelChannelPermutation_kernel<<<grid, block, 0, stream>>>(
        img, perm4, out4, nchunks, n_elems);
}

// Round 2
// 444.074 us; speedup vs baseline: 1.0120x; 1.0120x over previous
//
#include <hip/hip_runtime.h>

// out[n] = image[3*(n/3) + perm[n]], N = 4096*4096*3 floats.
// R6: R4's verified structure (coalesced float4 per chunk, wave shuffles for
// neighbor floats, masked per-wave edge loads, PLAIN stores) with two
// concurrency fixes and zero extra memory requests:
//  - ITERS=2 chunks per thread, all 4 main loads issued before any
//    consumption -> 2x in-flight bytes per wave, one vmcnt drain.
//  - block=1024 + __launch_bounds__(1024): 2 blocks/CU = 32 waves/CU (100%
//    occupancy; R4 sat at 76% with block=256).
//  - p = c % 3 offset trick from R5 (verified correct there) instead of 4x
//    magic-division per chunk. 1024 % 3 == 1, so p rotates by 1 per iter.
// R5 post-mortem: its lo/hi float2 loads added ~201MB of requested bytes
// (+60% line-touches) and pushed request throughput to 4.8 TB/s yet ran 17%
// slower -> the request path is the scarce resource; never spend it.

typedef float f32x4 __attribute__((ext_vector_type(4)));
typedef int   i32x4 __attribute__((ext_vector_type(4)));

#define ITERS 2
#define BLOCK 1024   // 1024 % 3 == 1 (p rotates by 1 per iter); 1024 % 64 == 0

__device__ __forceinline__ float sel8(float c0, float c1, float c2, float c3,
                                      float c4, float c5, float c6, float c7,
                                      int idx) {
    // 8-way select, 7 v_cndmask tree (idx in [0,7])
    float s01 = (idx & 1) ? c1 : c0;
    float s23 = (idx & 1) ? c3 : c2;
    float s45 = (idx & 1) ? c5 : c4;
    float s67 = (idx & 1) ? c7 : c6;
    float s03 = (idx & 2) ? s23 : s01;
    float s47 = (idx & 2) ? s67 : s45;
    return (idx & 4) ? s47 : s03;
}

__global__ __launch_bounds__(BLOCK) void PerPixelChannelPermutation_kernel(
    const float* __restrict__ img, const i32x4* __restrict__ perm4,
    f32x4* __restrict__ out4, int nchunks, int n_elems) {
    const int tid = threadIdx.x;
    const int c0  = blockIdx.x * (BLOCK * ITERS) + tid;
    if (c0 >= nchunks) return;

    const f32x4* img4 = (const f32x4*)img;

    f32x4 v[ITERS];
    i32x4 q[ITERS];
    int   cc[ITERS];

    // Phase 1: all main loads issued back-to-back -> 64B/lane in flight.
#pragma unroll
    for (int i = 0; i < ITERS; ++i) {
        int c = c0 + i * BLOCK;
        cc[i] = c;
        int cl = (c < nchunks) ? c : (nchunks - 1);  // tail-safe (store guarded)
        v[i] = img4[cl];   // img[4c .. 4c+3], lane-contiguous 16B
        q[i] = perm4[cl];  // perm[4c .. 4c+3], lane-contiguous 16B
    }

    // Phase 2: batched cross-lane shuffles (independent of each other).
    float pm2[ITERS], pm1[ITERS], nx0[ITERS], nx1[ITERS];
#pragma unroll
    for (int i = 0; i < ITERS; ++i) {
        pm2[i] = __shfl_up(v[i].z, 1);    // img[4c-2]
        pm1[i] = __shfl_up(v[i].w, 1);    // img[4c-1]
        nx0[i] = __shfl_down(v[i].x, 1);  // img[4c+4]
        nx1[i] = __shfl_down(v[i].y, 1);  // img[4c+5]
    }

    // Phase 3: per-wave edge patches (2 masked scalar loads per iter).
    const int lane = tid & 63;
    if (lane == 0) {
#pragma unroll
        for (int i = 0; i < ITERS; ++i) {
            int cl = (cc[i] < nchunks) ? cc[i] : (nchunks - 1);
            int b = cl * 4 - 2; if (b < 0) b = 0;  // c==0: idx 0,1 unreachable
            pm2[i] = img[b];
            pm1[i] = img[b + 1];
        }
    }
    if (lane == 63) {
#pragma unroll
        for (int i = 0; i < ITERS; ++i) {
            int cl = (cc[i] < nchunks) ? cc[i] : (nchunks - 1);
            int b = cl * 4 + 4; if (b > n_elems - 2) b = n_elems - 2;
            nx0[i] = img[b];   // last chunk: idx 6,7 unreachable, clamp safe
            nx1[i] = img[b + 1];
        }
    }

    // Phase 4: selects + stores. p = (4c) % 3 = c % 3; BLOCK == 1 mod 3.
    const int p0 = c0 % 3;  // one magic-mul sequence for the whole thread
#pragma unroll
    for (int i = 0; i < ITERS; ++i) {
        int p = p0 + i;
        if (p >= 3) p -= 3;  // i <= 1, p0 <= 2 -> one wrap suffices

        // candidates [pm2,pm1,v.x,v.y,v.z,v.w,nx0,nx1] = img[4c-2 .. 4c+5]
        // idx_k = off_k + perm_k; p=0: {2,2,2,5}  p=1: {1,1,4,4}  p=2: {0,3,3,3}
        const int off0 = 2 - p;
        const int off3 = 5 - p;
        const int off1 = (p == 0) ? 2 : ((p == 1) ? 1 : 3);
        const int off2 = (p == 0) ? 2 : ((p == 1) ? 4 : 3);

        f32x4 o;
        o.x = sel8(pm2[i], pm1[i], v[i].x, v[i].y, v[i].z, v[i].w,
                   nx0[i], nx1[i], off0 + q[i].x);
        o.y = sel8(pm2[i], pm1[i], v[i].x, v[i].y, v[i].z, v[i].w,
                   nx0[i], nx1[i], off1 + q[i].y);
        o.z = sel8(pm2[i], pm1[i], v[i].x, v[i].y, v[i].z, v[i].w,
                   nx0[i], nx1[i], off2 + q[i].z);
        o.w = sel8(pm2[i], pm1[i], v[i].x, v[i].y, v[i].z, v[i].w,
                   nx0[i], nx1[i], off3 + q[i].w);

        if (cc[i] < nchunks) out4[cc[i]] = o;  // coalesced, plain store
    }
}

extern "C" void kernel_launch(void* const* d_in, const int* in_sizes, int n_in,
                              void* d_out, int out_size, void* d_ws, size_t ws_size,
                              hipStream_t stream) {
    const float* img   = (const float*)d_in[0];
    const i32x4* perm4 = (const i32x4*)d_in[1];
    f32x4*       out4  = (f32x4*)d_out;

    const int n_elems = in_sizes[0];   // 4096*4096*3 = 50,331,648
    const int nchunks = n_elems / 4;   // one output float4 per chunk

    const int per_block = BLOCK * ITERS;
    const int grid = (nchunks + per_block - 1) / per_block;  // 6144, exact
    PerPixelChannelPermutation_kernel<<<grid, BLOCK, 0, stream>>>(
        img, perm4, out4, nchunks, n_elems);
}

// Round 4
// 440.536 us; speedup vs baseline: 1.0201x; 1.0080x over previous
//
#include <hip/hip_runtime.h>

// out[n] = image[3*(n/3) + perm[n]], N = 4096*4096*3 floats.
// R7 (resubmit — prior round was an infra failure, kernel never ran):
// R4's verified coalesced structure, decoupled retest of ITERS batching:
//  - BLOCK=256 (R4's occupancy regime; R6's block=1024 dropped occupancy
//    76%->63% and regressed).
//  - ITERS=2 chunks/thread: main loads for both chunks issued back-to-back
//    (32B/lane in flight) before any consumption.
//  - Edge patches HOISTED to phase 1: masked lane-0/63 loads issue into
//    temps while main loads are in flight, merged after the shuffles.
//    R4 had 3 serialized waits (vmcnt -> lgkm -> vmcnt); R7 has 2,
//    overlapped.
//  - p = c % 3 offset trick (verified R5/R6): no per-element magic division.
//    256 % 3 == 1 -> p rotates by 1 per iter.
//  - Plain coalesced stores, zero extra requested bytes (R5 lesson).

typedef float f32x4 __attribute__((ext_vector_type(4)));
typedef int   i32x4 __attribute__((ext_vector_type(4)));

#define ITERS 2
#define BLOCK 256   // 256 % 3 == 1; 4 waves/block

__device__ __forceinline__ float sel8(float c0, float c1, float c2, float c3,
                                      float c4, float c5, float c6, float c7,
                                      int idx) {
    // 8-way select, 7 v_cndmask tree (idx in [0,7])
    float s01 = (idx & 1) ? c1 : c0;
    float s23 = (idx & 1) ? c3 : c2;
    float s45 = (idx & 1) ? c5 : c4;
    float s67 = (idx & 1) ? c7 : c6;
    float s03 = (idx & 2) ? s23 : s01;
    float s47 = (idx & 2) ? s67 : s45;
    return (idx & 4) ? s47 : s03;
}

__global__ __launch_bounds__(BLOCK) void PerPixelChannelPermutation_kernel(
    const float* __restrict__ img, const i32x4* __restrict__ perm4,
    f32x4* __restrict__ out4, int nchunks, int n_elems) {
    const int tid  = threadIdx.x;
    const int c0   = blockIdx.x * (BLOCK * ITERS) + tid;
    if (c0 >= nchunks) return;
    const int lane = tid & 63;

    const f32x4* img4 = (const f32x4*)img;

    f32x4 v[ITERS];
    i32x4 q[ITERS];
    int   cc[ITERS];

    // ---- Phase 1a: main loads for all iters, back-to-back ----
#pragma unroll
    for (int i = 0; i < ITERS; ++i) {
        int c = c0 + i * BLOCK;
        cc[i] = c;
        int cl = (c < nchunks) ? c : c0;  // tail-safe (stores guarded; exact grid)
        v[i] = img4[cl];   // img[4c .. 4c+3], lane-contiguous 16B
        q[i] = perm4[cl];  // perm[4c .. 4c+3], lane-contiguous 16B
    }

    // ---- Phase 1b: masked edge loads issued WHILE main loads in flight ----
    float elo0[ITERS], elo1[ITERS], ehi0[ITERS], ehi1[ITERS];
    if (lane == 0) {
#pragma unroll
        for (int i = 0; i < ITERS; ++i) {
            int cl = (cc[i] < nchunks) ? cc[i] : c0;
            int b = cl * 4 - 2; if (b < 0) b = 0;  // c==0: idx 0,1 unreachable
            elo0[i] = img[b];
            elo1[i] = img[b + 1];
        }
    }
    if (lane == 63) {
#pragma unroll
        for (int i = 0; i < ITERS; ++i) {
            int cl = (cc[i] < nchunks) ? cc[i] : c0;
            int b = cl * 4 + 4; if (b > n_elems - 2) b = n_elems - 2;
            ehi0[i] = img[b];   // last chunk: idx 6,7 unreachable, clamp safe
            ehi1[i] = img[b + 1];
        }
    }

    // ---- Phase 2: cross-lane shuffles (waits only on v, edge loads still
    //      in flight) ----
    float pm2[ITERS], pm1[ITERS], nx0[ITERS], nx1[ITERS];
#pragma unroll
    for (int i = 0; i < ITERS; ++i) {
        pm2[i] = __shfl_up(v[i].z, 1);    // img[4c-2]
        pm1[i] = __shfl_up(v[i].w, 1);    // img[4c-1]
        nx0[i] = __shfl_down(v[i].x, 1);  // img[4c+4]
        nx1[i] = __shfl_down(v[i].y, 1);  // img[4c+5]
    }

    // ---- Phase 3: merge edge lanes (cndmask, no loads) ----
#pragma unroll
    for (int i = 0; i < ITERS; ++i) {
        if (lane == 0)  { pm2[i] = elo0[i]; pm1[i] = elo1[i]; }
        if (lane == 63) { nx0[i] = ehi0[i]; nx1[i] = ehi1[i]; }
    }

    // ---- Phase 4: selects + stores. p = (4c)%3 = c%3; BLOCK == 1 mod 3 ----
    const int p0 = c0 % 3;  // one magic-mul for the whole thread
#pragma unroll
    for (int i = 0; i < ITERS; ++i) {
        int p = p0 + i;
        if (p >= 3) p -= 3;  // i <= 1, p0 <= 2 -> one wrap suffices

        // candidates [pm2,pm1,v.x,v.y,v.z,v.w,nx0,nx1] = img[4c-2 .. 4c+5]
        // idx_k = off_k + perm_k; p=0: {2,2,2,5}  p=1: {1,1,4,4}  p=2: {0,3,3,3}
        const int off0 = 2 - p;
        const int off3 = 5 - p;
        const int off1 = (p == 0) ? 2 : ((p == 1) ? 1 : 3);
        const int off2 = (p == 0) ? 2 : ((p == 1) ? 4 : 3);

        f32x4 o;
        o.x = sel8(pm2[i], pm1[i], v[i].x, v[i].y, v[i].z, v[i].w,
                   nx0[i], nx1[i], off0 + q[i].x);
        o.y = sel8(pm2[i], pm1[i], v[i].x, v[i].y, v[i].z, v[i].w,
                   nx0[i], nx1[i], off1 + q[i].y);
        o.z = sel8(pm2[i], pm1[i], v[i].x, v[i].y, v[i].z, v[i].w,
                   nx0[i], nx1[i], off2 + q[i].z);
        o.w = sel8(pm2[i], pm1[i], v[i].x, v[i].y, v[i].z, v[i].w,
                   nx0[i], nx1[i], off3 + q[i].w);

        if (cc[i] < nchunks) out4[cc[i]] = o;  // coalesced, plain store
    }
}

extern "C" void kernel_launch(void* const* d_in, const int* in_sizes, int n_in,
                              void* d_out, int out_size, void* d_ws, size_t ws_size,
                              hipStream_t stream) {
    const float* img   = (const float*)d_in[0];
    const i32x4* perm4 = (const i32x4*)d_in[1];
    f32x4*       out4  = (f32x4*)d_out;

    const int n_elems = in_sizes[0];   // 4096*4096*3 = 50,331,648
    const int nchunks = n_elems / 4;   // one output float4 per chunk

    const int per_block = BLOCK * ITERS;
    const int grid = (nchunks + per_block - 1) / per_block;  // 24576, exact
    PerPixelChannelPermutation_kernel<<<grid, BLOCK, 0, stream>>>(
        img, perm4, out4, nchunks, n_elems);
}

// Round 5
// 432.501 us; speedup vs baseline: 1.0391x; 1.0186x over previous
//
#include <hip/hip_runtime.h>

// out[n] = image[3*(n/3) + perm[n]], N = 4096*4096*3 floats.
// R8: R4's exact coalesced skeleton (1 chunk/thread, float4 loads/stores,
// sel8, p = c%3 static offsets) with the cross-lane machinery replaced by
// LDS neighbor exchange:
//  - ds_write_b128 own quad -> barrier -> two contiguous ds_read_b128 for
//    neighbor quads (2 lanes/bank = conflict-free, m136). Replaces 4
//    ds_bpermute serial chain.
//  - Edge patches: 2 threads per BLOCK (tid 0 / 255) instead of 2 lanes per
//    WAVE (8 threads/block in R4) -> 4x less exec-mask divergence, and the
//    patch loads issue while main loads are still in flight.
//  - Requests stay at the 604 MB floor: zero extra global bytes (R5 lesson).
//  - ITERS=1, no bookkeeping (R7 lesson: batching bought nothing, its
//    bookkeeping cost ~5 us).
// Grid is exact: nchunks = 12,582,912 = 49152 * 256, so no tail guard
// (a guarded early-return before __syncthreads would be a deadlock hazard).

typedef float f32x4 __attribute__((ext_vector_type(4)));
typedef int   i32x4 __attribute__((ext_vector_type(4)));

#define BLOCK 256

__device__ __forceinline__ float sel8(float c0, float c1, float c2, float c3,
                                      float c4, float c5, float c6, float c7,
                                      int idx) {
    // 8-way select, 7 v_cndmask tree (idx in [0,7])
    float s01 = (idx & 1) ? c1 : c0;
    float s23 = (idx & 1) ? c3 : c2;
    float s45 = (idx & 1) ? c5 : c4;
    float s67 = (idx & 1) ? c7 : c6;
    float s03 = (idx & 2) ? s23 : s01;
    float s47 = (idx & 2) ? s67 : s45;
    return (idx & 4) ? s47 : s03;
}

__global__ __launch_bounds__(BLOCK) void PerPixelChannelPermutation_kernel(
    const float* __restrict__ img, const i32x4* __restrict__ perm4,
    f32x4* __restrict__ out4, int nchunks, int n_elems) {
    __shared__ f32x4 sv[BLOCK];

    const int tid = threadIdx.x;
    const int c   = blockIdx.x * BLOCK + tid;  // exact grid, no tail
    const int c4  = c * 4;

    const f32x4* img4 = (const f32x4*)img;

    // Main loads: img first (ds_write waits only on it, perm stays in
    // flight through the barrier), both lane-contiguous 16B.
    const f32x4 v  = img4[c];   // img[4c .. 4c+3]
    const i32x4 qq = perm4[c];  // perm[4c .. 4c+3]

    // Edge patch loads issued early (2 threads per block), in flight
    // across the barrier.
    float e0 = 0.f, e1 = 0.f;
    if (tid == 0) {
        int b = c4 - 2; if (b < 0) b = 0;  // c==0: idx 0,1 unreachable, clamp safe
        e0 = img[b];
        e1 = img[b + 1];
    }
    if (tid == BLOCK - 1) {
        int b = c4 + 4; if (b > n_elems - 2) b = n_elems - 2;  // last chunk: idx 6,7 unreachable
        e0 = img[b];
        e1 = img[b + 1];
    }

    sv[tid] = v;            // ds_write_b128, contiguous: conflict-free
    __syncthreads();

    // Neighbor quads via contiguous ds_read_b128 (2 lanes/bank = free).
    const int il = (tid == 0)         ? 0         : tid - 1;
    const int ih = (tid == BLOCK - 1) ? BLOCK - 1 : tid + 1;
    const f32x4 L = sv[il];
    const f32x4 H = sv[ih];

    float pm2 = L.z, pm1 = L.w;   // img[4c-2], img[4c-1]
    float nx0 = H.x, nx1 = H.y;   // img[4c+4], img[4c+5]
    if (tid == 0)         { pm2 = e0; pm1 = e1; }
    if (tid == BLOCK - 1) { nx0 = e0; nx1 = e1; }

    // p = (4c) % 3 = c % 3; candidate idx_k = off_k + perm_k over
    // [pm2, pm1, v.x, v.y, v.z, v.w, nx0, nx1] = img[4c-2 .. 4c+5]
    //   p=0: offs {2,2,2,5}   p=1: {1,1,4,4}   p=2: {0,3,3,3}
    const int p = c % 3;
    const int off0 = 2 - p;
    const int off3 = 5 - p;
    const int off1 = (p == 0) ? 2 : ((p == 1) ? 1 : 3);
    const int off2 = (p == 0) ? 2 : ((p == 1) ? 4 : 3);

    f32x4 o;
    o.x = sel8(pm2, pm1, v.x, v.y, v.z, v.w, nx0, nx1, off0 + qq.x);
    o.y = sel8(pm2, pm1, v.x, v.y, v.z, v.w, nx0, nx1, off1 + qq.y);
    o.z = sel8(pm2, pm1, v.x, v.y, v.z, v.w, nx0, nx1, off2 + qq.z);
    o.w = sel8(pm2, pm1, v.x, v.y, v.z, v.w, nx0, nx1, off3 + qq.w);

    out4[c] = o;  // coalesced, plain store
}

extern "C" void kernel_launch(void* const* d_in, const int* in_sizes, int n_in,
                              void* d_out, int out_size, void* d_ws, size_t ws_size,
                              hipStream_t stream) {
    const float* img   = (const float*)d_in[0];
    const i32x4* perm4 = (const i32x4*)d_in[1];
    f32x4*       out4  = (f32x4*)d_out;

    const int n_elems = in_sizes[0];   // 4096*4096*3 = 50,331,648
    const int nchunks = n_elems / 4;   // 12,582,912 = 49152 * 256 (exact)

    const int grid = nchunks / BLOCK;  // 49152, exact — no tail
    PerPixelChannelPermutation_kernel<<<grid, BLOCK, 0, stream>>>(
        img, perm4, out4, nchunks, n_elems);
}